// Round 1
// baseline (869.036 us; speedup 1.0000x reference)
//
#include <hip/hip_runtime.h>

// Problem constants (from reference): TOKENS=8192, N=4096, K=4096, GROUP=128
#define M_TOK 8192
#define N_OUT 4096
#define K_DIM 4096
#define NGROUPS (K_DIM / 128)

#define BM 128
#define BN 128
#define BK 32
#define LDS_STRIDE 40   // bf16 elems per row: 32 + 8 pad -> 80B stride breaks bank conflicts

typedef __bf16 bf16x8 __attribute__((ext_vector_type(8)));
typedef __bf16 bf16x4 __attribute__((ext_vector_type(4)));
typedef float  f32x4  __attribute__((ext_vector_type(4)));

__global__ __launch_bounds__(256)
void qlinear_mfma_kernel(const float* __restrict__ x,
                         const int*   __restrict__ wq,
                         const float* __restrict__ scales,
                         const float* __restrict__ zeros,
                         const float* __restrict__ bias,
                         float*       __restrict__ out)
{
    __shared__ __bf16 As[BM * LDS_STRIDE];
    __shared__ __bf16 Bs[BN * LDS_STRIDE];

    const int tid  = threadIdx.x;
    const int m0   = blockIdx.x * BM;
    const int n0   = blockIdx.y * BN;

    const int wave = tid >> 6;          // 0..3
    const int lane = tid & 63;
    const int wm   = (wave & 1) * 64;   // wave's m offset within tile
    const int wn   = (wave >> 1) * 64;  // wave's n offset within tile
    const int lrow = lane & 15;
    const int quad = lane >> 4;

    // staging assignment: 8 threads per row cover 32 cols (4 each), 32 rows/pass, 4 passes
    const int srow  = tid >> 3;         // 0..31
    const int scol  = (tid & 7) * 4;    // column offset in elements

    f32x4 acc[4][4];
#pragma unroll
    for (int i = 0; i < 4; i++)
#pragma unroll
        for (int j = 0; j < 4; j++)
            acc[i][j] = (f32x4){0.f, 0.f, 0.f, 0.f};

    for (int k0 = 0; k0 < K_DIM; k0 += BK) {
        const int g = k0 >> 7;  // group index, constant across the BK=32 window

        // ---- stage A tile: x[m0+row][k0+scol .. +3], fp32 -> bf16 ----
#pragma unroll
        for (int rr = 0; rr < 4; rr++) {
            const int row = srow + rr * 32;
            const float4 v = *(const float4*)(x + (size_t)(m0 + row) * K_DIM + k0 + scol);
            bf16x4 b;
            b[0] = (__bf16)v.x; b[1] = (__bf16)v.y;
            b[2] = (__bf16)v.z; b[3] = (__bf16)v.w;
            *(bf16x4*)&As[row * LDS_STRIDE + scol] = b;
        }

        // ---- stage B tile: dequant wq[n0+row][k0+scol .. +3] -> bf16 ----
#pragma unroll
        for (int rr = 0; rr < 4; rr++) {
            const int row = srow + rr * 32;
            const int4 q = *(const int4*)(wq + (size_t)(n0 + row) * K_DIM + k0 + scol);
            const float s = scales[(n0 + row) * NGROUPS + g];
            const float z = zeros [(n0 + row) * NGROUPS + g];
            bf16x4 b;
            b[0] = (__bf16)fmaf((float)q.x, s, z);
            b[1] = (__bf16)fmaf((float)q.y, s, z);
            b[2] = (__bf16)fmaf((float)q.z, s, z);
            b[3] = (__bf16)fmaf((float)q.w, s, z);
            *(bf16x4*)&Bs[row * LDS_STRIDE + scol] = b;
        }

        __syncthreads();

        // ---- fragments from LDS ----
        bf16x8 af[4], bfr[4];
#pragma unroll
        for (int i = 0; i < 4; i++) {
            af[i]  = *(const bf16x8*)&As[(wm + i * 16 + lrow) * LDS_STRIDE + quad * 8];
            bfr[i] = *(const bf16x8*)&Bs[(wn + i * 16 + lrow) * LDS_STRIDE + quad * 8];
        }

#pragma unroll
        for (int i = 0; i < 4; i++)
#pragma unroll
            for (int j = 0; j < 4; j++)
                acc[i][j] = __builtin_amdgcn_mfma_f32_16x16x32_bf16(af[i], bfr[j], acc[i][j], 0, 0, 0);

        __syncthreads();
    }

    // ---- epilogue: D row=(lane>>4)*4+reg, col=lane&15 ; add bias ----
#pragma unroll
    for (int j = 0; j < 4; j++) {
        const int col = n0 + wn + j * 16 + lrow;
        const float bv = bias[col];
#pragma unroll
        for (int i = 0; i < 4; i++) {
            const int rowb = m0 + wm + i * 16 + quad * 4;
#pragma unroll
            for (int r = 0; r < 4; r++)
                out[(size_t)(rowb + r) * N_OUT + col] = acc[i][j][r] + bv;
        }
    }
}

extern "C" void kernel_launch(void* const* d_in, const int* in_sizes, int n_in,
                              void* d_out, int out_size, void* d_ws, size_t ws_size,
                              hipStream_t stream) {
    const float* x      = (const float*)d_in[0];
    const int*   wq     = (const int*)  d_in[1];
    const float* scales = (const float*)d_in[2];
    const float* zeros  = (const float*)d_in[3];
    const float* bias   = (const float*)d_in[4];
    float*       out    = (float*)d_out;

    dim3 grid(M_TOK / BM, N_OUT / BN);
    qlinear_mfma_kernel<<<grid, 256, 0, stream>>>(x, wq, scales, zeros, bias, out);
}

// Round 2
// 584.331 us; speedup vs baseline: 1.4872x; 1.4872x over previous
//
#include <hip/hip_runtime.h>

#define M_TOK 8192
#define N_OUT 4096
#define K_DIM 4096
#define NGROUPS 32          // K/128

typedef __bf16 bf16x8 __attribute__((ext_vector_type(8)));
typedef __bf16 bf16x4 __attribute__((ext_vector_type(4)));
typedef float  f32x4  __attribute__((ext_vector_type(4)));

#define GLOBAL_CVP const __attribute__((address_space(1))) void*
#define LDS_VP __attribute__((address_space(3))) void*

// ---------------- prep: x fp32 -> bf16 ----------------
__global__ __launch_bounds__(256)
void convert_x_kernel(const float* __restrict__ x, __bf16* __restrict__ xb) {
    const size_t total = (size_t)M_TOK * K_DIM / 8;   // bf16x8 chunks
    for (size_t i = (size_t)blockIdx.x * blockDim.x + threadIdx.x; i < total;
         i += (size_t)gridDim.x * blockDim.x) {
        const float4 v0 = ((const float4*)x)[2 * i];
        const float4 v1 = ((const float4*)x)[2 * i + 1];
        bf16x8 b;
        b[0] = (__bf16)v0.x; b[1] = (__bf16)v0.y; b[2] = (__bf16)v0.z; b[3] = (__bf16)v0.w;
        b[4] = (__bf16)v1.x; b[5] = (__bf16)v1.y; b[6] = (__bf16)v1.z; b[7] = (__bf16)v1.w;
        ((bf16x8*)xb)[i] = b;
    }
}

// ---------------- prep: dequant wq int32 -> bf16 ----------------
__global__ __launch_bounds__(256)
void dequant_w_kernel(const int* __restrict__ wq, const float* __restrict__ scales,
                      const float* __restrict__ zeros, __bf16* __restrict__ wb) {
    const size_t total = (size_t)N_OUT * K_DIM / 8;
    for (size_t i = (size_t)blockIdx.x * blockDim.x + threadIdx.x; i < total;
         i += (size_t)gridDim.x * blockDim.x) {
        const int4 q0 = ((const int4*)wq)[2 * i];
        const int4 q1 = ((const int4*)wq)[2 * i + 1];
        const size_t e = i * 8;
        const int row = (int)(e >> 12);      // / 4096
        const int g   = ((int)e & 4095) >> 7; // group within row (8 | 128, no straddle)
        const float s = scales[row * NGROUPS + g];
        const float z = zeros [row * NGROUPS + g];
        bf16x8 b;
        b[0] = (__bf16)fmaf((float)q0.x, s, z);
        b[1] = (__bf16)fmaf((float)q0.y, s, z);
        b[2] = (__bf16)fmaf((float)q0.z, s, z);
        b[3] = (__bf16)fmaf((float)q0.w, s, z);
        b[4] = (__bf16)fmaf((float)q1.x, s, z);
        b[5] = (__bf16)fmaf((float)q1.y, s, z);
        b[6] = (__bf16)fmaf((float)q1.z, s, z);
        b[7] = (__bf16)fmaf((float)q1.w, s, z);
        ((bf16x8*)wb)[i] = b;
    }
}

// ---------------- main: bf16 GEMM, B^T input, m97 structure ----------------
// A [M,K] row-major bf16, B [N,K] row-major bf16, out[M,N] fp32 = A.B^T + bias
__global__ __launch_bounds__(256)
void gemm_bt_kernel(const __bf16* __restrict__ A, const __bf16* __restrict__ B,
                    const float* __restrict__ bias, float* __restrict__ out) {
    __shared__ __bf16 As[128 * 32];   // 8 KB, unpadded (global_load_lds layout rule)
    __shared__ __bf16 Bs[128 * 32];   // 8 KB

    const int tid  = threadIdx.x;
    const int wave = tid >> 6;
    const int lane = tid & 63;
    const int m0 = blockIdx.x * 128;
    const int n0 = blockIdx.y * 128;
    const int wm = (wave & 1) * 64;
    const int wn = (wave >> 1) * 64;
    const int lrow = lane & 15;
    const int quad = lane >> 4;

    // staging: wave w covers rows [w*32, w*32+32) of each tile; one
    // global_load_lds_dwordx4 covers 16 rows (64 lanes x 16 B = 1 KB)
    const int sbase = wave * 32;
    const int lr = lane >> 2;          // row within 16-row chunk
    const int lc = (lane & 3) * 8;     // element col within BK=32

    const __bf16* ap0 = A + (size_t)(m0 + sbase + lr) * K_DIM + lc;
    const __bf16* ap1 = ap0 + (size_t)16 * K_DIM;
    const __bf16* bp0 = B + (size_t)(n0 + sbase + lr) * K_DIM + lc;
    const __bf16* bp1 = bp0 + (size_t)16 * K_DIM;

    __bf16* la0 = &As[sbase * 32];
    __bf16* la1 = &As[(sbase + 16) * 32];
    __bf16* lb0 = &Bs[sbase * 32];
    __bf16* lb1 = &Bs[(sbase + 16) * 32];

    f32x4 acc[4][4];
#pragma unroll
    for (int i = 0; i < 4; i++)
#pragma unroll
        for (int j = 0; j < 4; j++)
            acc[i][j] = (f32x4){0.f, 0.f, 0.f, 0.f};

    for (int k0 = 0; k0 < K_DIM; k0 += 32) {
        __builtin_amdgcn_global_load_lds((GLOBAL_CVP)(ap0 + k0), (LDS_VP)la0, 16, 0, 0);
        __builtin_amdgcn_global_load_lds((GLOBAL_CVP)(ap1 + k0), (LDS_VP)la1, 16, 0, 0);
        __builtin_amdgcn_global_load_lds((GLOBAL_CVP)(bp0 + k0), (LDS_VP)lb0, 16, 0, 0);
        __builtin_amdgcn_global_load_lds((GLOBAL_CVP)(bp1 + k0), (LDS_VP)lb1, 16, 0, 0);
        __syncthreads();

        bf16x8 af[4], bfr[4];
#pragma unroll
        for (int i = 0; i < 4; i++) {
            af[i]  = *(const bf16x8*)&As[(wm + i * 16 + lrow) * 32 + quad * 8];
            bfr[i] = *(const bf16x8*)&Bs[(wn + i * 16 + lrow) * 32 + quad * 8];
        }

#pragma unroll
        for (int i = 0; i < 4; i++)
#pragma unroll
            for (int j = 0; j < 4; j++)
                acc[i][j] = __builtin_amdgcn_mfma_f32_16x16x32_bf16(af[i], bfr[j], acc[i][j], 0, 0, 0);

        __syncthreads();
    }

    // epilogue: D row=(lane>>4)*4+reg, col=lane&15 ; add bias
#pragma unroll
    for (int j = 0; j < 4; j++) {
        const int col = n0 + wn + j * 16 + lrow;
        const float bv = bias[col];
#pragma unroll
        for (int i = 0; i < 4; i++) {
            const int rowb = m0 + wm + i * 16 + quad * 4;
#pragma unroll
            for (int r = 0; r < 4; r++)
                out[(size_t)(rowb + r) * N_OUT + col] = acc[i][j][r] + bv;
        }
    }
}

// ---------------- fallback (round-1 fused kernel, used if ws too small) ----
#define LDS_STRIDE 40
__global__ __launch_bounds__(256)
void qlinear_fused_kernel(const float* __restrict__ x,
                          const int*   __restrict__ wq,
                          const float* __restrict__ scales,
                          const float* __restrict__ zeros,
                          const float* __restrict__ bias,
                          float*       __restrict__ out)
{
    __shared__ __bf16 As[128 * LDS_STRIDE];
    __shared__ __bf16 Bs[128 * LDS_STRIDE];
    const int tid  = threadIdx.x;
    const int m0   = blockIdx.x * 128;
    const int n0   = blockIdx.y * 128;
    const int wave = tid >> 6;
    const int lane = tid & 63;
    const int wm   = (wave & 1) * 64;
    const int wn   = (wave >> 1) * 64;
    const int lrow = lane & 15;
    const int quad = lane >> 4;
    const int srow = tid >> 3;
    const int scol = (tid & 7) * 4;

    f32x4 acc[4][4];
#pragma unroll
    for (int i = 0; i < 4; i++)
#pragma unroll
        for (int j = 0; j < 4; j++)
            acc[i][j] = (f32x4){0.f, 0.f, 0.f, 0.f};

    for (int k0 = 0; k0 < K_DIM; k0 += 32) {
        const int g = k0 >> 7;
#pragma unroll
        for (int rr = 0; rr < 4; rr++) {
            const int row = srow + rr * 32;
            const float4 v = *(const float4*)(x + (size_t)(m0 + row) * K_DIM + k0 + scol);
            bf16x4 b;
            b[0] = (__bf16)v.x; b[1] = (__bf16)v.y;
            b[2] = (__bf16)v.z; b[3] = (__bf16)v.w;
            *(bf16x4*)&As[row * LDS_STRIDE + scol] = b;
        }
#pragma unroll
        for (int rr = 0; rr < 4; rr++) {
            const int row = srow + rr * 32;
            const int4 q = *(const int4*)(wq + (size_t)(n0 + row) * K_DIM + k0 + scol);
            const float s = scales[(n0 + row) * NGROUPS + g];
            const float z = zeros [(n0 + row) * NGROUPS + g];
            bf16x4 b;
            b[0] = (__bf16)fmaf((float)q.x, s, z);
            b[1] = (__bf16)fmaf((float)q.y, s, z);
            b[2] = (__bf16)fmaf((float)q.z, s, z);
            b[3] = (__bf16)fmaf((float)q.w, s, z);
            *(bf16x4*)&Bs[row * LDS_STRIDE + scol] = b;
        }
        __syncthreads();
        bf16x8 af[4], bfr[4];
#pragma unroll
        for (int i = 0; i < 4; i++) {
            af[i]  = *(const bf16x8*)&As[(wm + i * 16 + lrow) * LDS_STRIDE + quad * 8];
            bfr[i] = *(const bf16x8*)&Bs[(wn + i * 16 + lrow) * LDS_STRIDE + quad * 8];
        }
#pragma unroll
        for (int i = 0; i < 4; i++)
#pragma unroll
            for (int j = 0; j < 4; j++)
                acc[i][j] = __builtin_amdgcn_mfma_f32_16x16x32_bf16(af[i], bfr[j], acc[i][j], 0, 0, 0);
        __syncthreads();
    }
#pragma unroll
    for (int j = 0; j < 4; j++) {
        const int col = n0 + wn + j * 16 + lrow;
        const float bv = bias[col];
#pragma unroll
        for (int i = 0; i < 4; i++) {
            const int rowb = m0 + wm + i * 16 + quad * 4;
#pragma unroll
            for (int r = 0; r < 4; r++)
                out[(size_t)(rowb + r) * N_OUT + col] = acc[i][j][r] + bv;
        }
    }
}

extern "C" void kernel_launch(void* const* d_in, const int* in_sizes, int n_in,
                              void* d_out, int out_size, void* d_ws, size_t ws_size,
                              hipStream_t stream) {
    const float* x      = (const float*)d_in[0];
    const int*   wq     = (const int*)  d_in[1];
    const float* scales = (const float*)d_in[2];
    const float* zeros  = (const float*)d_in[3];
    const float* bias   = (const float*)d_in[4];
    float*       out    = (float*)d_out;

    const size_t xb_bytes = (size_t)M_TOK * K_DIM * 2;   // 67.1 MB
    const size_t wb_bytes = (size_t)N_OUT * K_DIM * 2;   // 33.6 MB

    if (ws_size >= xb_bytes + wb_bytes) {
        __bf16* xb = (__bf16*)d_ws;
        __bf16* wb = (__bf16*)((char*)d_ws + xb_bytes);
        convert_x_kernel<<<4096, 256, 0, stream>>>(x, xb);
        dequant_w_kernel<<<2048, 256, 0, stream>>>(wq, scales, zeros, wb);
        dim3 grid(M_TOK / 128, N_OUT / 128);
        gemm_bt_kernel<<<grid, 256, 0, stream>>>(xb, wb, bias, out);
    } else {
        dim3 grid(M_TOK / 128, N_OUT / 128);
        qlinear_fused_kernel<<<grid, 256, 0, stream>>>(x, wq, scales, zeros, bias, out);
    }
}